// Round 5
// baseline (303.970 us; speedup 1.0000x reference)
//
#include <hip/hip_runtime.h>
#include <hip/hip_bf16.h>
#include <math.h>

#define B_     128
#define DIM_   512
#define HEADS_ 8
#define HD_    64
#define N_     196
#define NP_    224            // padded n (14 tiles of 16)
#define NROW_  208            // padded n rows (13 tiles of 16) for EB
#define SCALE_ 0.125f
#define BSTRIDE (DIM_ * N_)
#define J_     (B_ * NP_)     // 28672 GEMM columns (b*224+n)

typedef unsigned short u16;
typedef unsigned int   u32;
typedef __attribute__((ext_vector_type(8))) short bf16x8;   // 8 bf16 = 4 VGPRs
typedef __attribute__((ext_vector_type(4))) float f32x4;

__device__ __forceinline__ u16 f2bf(float f) {              // RNE fp32->bf16
    u32 u = __float_as_uint(f);
    return (u16)((u + 0x7fffu + ((u >> 16) & 1u)) >> 16);
}
__device__ __forceinline__ void gload_lds16(const u16* g, u16* l) {
    // async global->LDS, 16B/lane; LDS dest = wave-uniform base + lane*16
    __builtin_amdgcn_global_load_lds(
        (const __attribute__((address_space(1))) void*)g,
        (__attribute__((address_space(3))) void*)l, 16, 0, 0);
}

// ---------------------------------------------------------------------------
// fp32 -> bf16 elementwise, two tensors in one launch (y=0: qkv_w, y=1: proj).
// ---------------------------------------------------------------------------
__global__ __launch_bounds__(256) void cvt_bf2(
    const float* __restrict__ a, u16* __restrict__ da, int n4a,
    const float* __restrict__ b, u16* __restrict__ db, int n4b)
{
    const int i = blockIdx.x * 256 + threadIdx.x;
    const float* src = blockIdx.y ? b : a;
    u16* dst = blockIdx.y ? db : da;
    const int n4 = blockIdx.y ? n4b : n4a;
    if (i < n4) {
        const float4 v = reinterpret_cast<const float4*>(src)[i];
        uint2 o;
        o.x = (u32)f2bf(v.x) | ((u32)f2bf(v.y) << 16);
        o.y = (u32)f2bf(v.z) | ((u32)f2bf(v.w) << 16);
        reinterpret_cast<uint2*>(dst)[i] = o;
    }
}

// ---------------------------------------------------------------------------
// x fp32 [b][512][196] -> XT bf16 [b][224][512] (pad rows garbage, masked
// downstream: EB=0 for m>=196, OT/out stores guarded for n>=196).
// ---------------------------------------------------------------------------
__global__ __launch_bounds__(256) void cvt_xT(
    const float* __restrict__ x, u16* __restrict__ XT)
{
    __shared__ float tile[64][65];
    const int t = threadIdx.x;
    const int jj = t & 63, ii = t >> 6;
    const int ct = blockIdx.x, ntb = blockIdx.y, b = blockIdx.z;
    const float* xb = x + ((size_t)b * DIM_ + ct * 64) * N_;
    const int n0 = ntb * 64;
    #pragma unroll
    for (int s = 0; s < 16; ++s) {
        const int i = ii + s * 4;
        const int n = n0 + jj;
        tile[i][jj] = (n < N_) ? xb[(size_t)i * N_ + n] : 0.f;
    }
    __syncthreads();
    u16* ot = XT + (size_t)b * NP_ * DIM_ + ct * 64;
    #pragma unroll
    for (int s = 0; s < 16; ++s) {
        const int nn = n0 + ii + s * 4;
        if (nn < N_) ot[(size_t)nn * DIM_ + jj] = f2bf(tile[jj][ii + s * 4]);
    }
}

// ---------------------------------------------------------------------------
// EB[h][208][224] = exp(bias[h][bidx[n][m]]) for n,m<196 else 0.
// ---------------------------------------------------------------------------
__global__ __launch_bounds__(256) void mk_eb(
    const float* __restrict__ biases, const int* __restrict__ bidx,
    float* __restrict__ EB)
{
    const int n = blockIdx.x, h = blockIdx.y;
    const int m = threadIdx.x;
    if (m < NP_) {
        float v = 0.f;
        if (n < N_ && m < N_) v = __expf(biases[h * N_ + bidx[n * N_ + m]]);
        EB[((size_t)h * NROW_ + n) * NP_ + m] = v;
    }
}

// ---------------------------------------------------------------------------
// 128x256 MFMA GEMM (8 waves = 2x4): C[M][28672] = W[M][512] . XT[...][512]^T.
// r10: r9's counted-vmcnt 3-buf REGRESSED (78->85us; T4 needs 8-phase fine
// interleave, coarse graft is null-negative per m196) -> reverted to the r8
// dbuf+syncthreads 2-phase loop. New lever: TLP. r8 ran ~2 blocks x 4 waves
// per CU with every pipe 75% idle (stall-bound: MfmaUtil 20, VALU 15, HBM 18,
// occupancy 27%). Now 512 thr / 8 waves per block, 128 rows x 256 cols,
// LDS dbuf = 2x(8+16) KB = 48 KB -> 3 blocks/CU x 8 waves = 24 waves/CU
// (VGPR ~76 -> 6 waves/SIMD fits exactly). Per-wave structure UNCHANGED
// (4x4 frags, same slot maps, 16 MFMA + 8 ds_read_b128/iter): parameter
// change only, inherits r8 template verification. A-staging traffic halves;
// 3 gload_lds/wave/iter (1A+2B) vs 4.
// XCD swizzle (verified r8: FETCH 87->34MB): 1-D grid, mt-fastest, bijective
// (NWG%8==0; 112*12=1344, 112*4=448).
// LDS slot map slot(row,chunk)=row*4+(chunk^((row>>1)&3)) via SOURCE chunk
// permutation (dest must be lane-contiguous) -> frag ds_read_b128 is 2-way
// bank-aliased = free (m136). r3 lesson: no waves_per_eu attribute.
// Epilogue QKV: qT/kT[b][h][n<=224][64] (8B stores), vS[b][h][d][224];
// pads stored unguarded -- EB=0 masks every pad contribution downstream.
// Epilogue proj: fp32 out[b][512][196], n guarded.
// ---------------------------------------------------------------------------
template<bool QKV>
__global__ __launch_bounds__(512) void gemm128(
    const u16* __restrict__ Bt, const u16* __restrict__ W,
    const float* __restrict__ bias,
    u16* __restrict__ o_q, u16* __restrict__ o_k, u16* __restrict__ o_v,
    float* __restrict__ o_f)
{
    __shared__ u16 As[2][128 * 32];     // 2 x 8 KB
    __shared__ u16 Bs[2][256 * 32];     // 2 x 16 KB (48 KB total)
    const int t = threadIdx.x;
    const int wave = t >> 6, lane = t & 63;
    const int m16 = lane & 15, quad = lane >> 4;

    constexpr int MT  = QKV ? 12 : 4;
    constexpr int NWG = (J_ / 256) * MT;
    const int bid = blockIdx.x;
    const int swz = (bid & 7) * (NWG / 8) + (bid >> 3);   // bijective XCD swizzle
    const int mt = swz % MT;                               // mt fastest
    const int jt = swz / MT;
    const int m0 = mt * 128, j0 = jt * 256;
    const int wy = wave >> 2, wx = wave & 3;     // wave tile: rows wy*64, cols wx*64

    // staging: A call c=wave (8 calls, 16 rows each); B call c=wave*2+cc (16
    // calls). lane's source row = c*16 + (lane>>2), source chunk =
    // (lane&3) ^ ((lane>>3)&3)  (slot map preserved from r8).
    const int srow  = (lane >> 2);               // + c*16
    const int schnk = (lane & 3) ^ ((lane >> 3) & 3);
    const u16* gA = W  + (size_t)(m0 + wave * 16 + srow) * DIM_ + schnk * 8;
    const u16* gB = Bt + (size_t)(j0 + wave * 32 + srow) * DIM_ + schnk * 8;

    // frag read column: col = quad ^ ((m16>>1)&3); u16 offset row*32 + col*8
    const int rcol = (quad ^ ((m16 >> 1) & 3)) * 8;

    f32x4 acc[4][4];
    const f32x4 z4 = {0.f, 0.f, 0.f, 0.f};
    #pragma unroll
    for (int fi = 0; fi < 4; ++fi)
        #pragma unroll
        for (int fj = 0; fj < 4; ++fj) acc[fi][fj] = z4;

    // prologue: stage kt=0 into buf 0
    gload_lds16(gA, As[0] + wave * 512);
    #pragma unroll
    for (int cc = 0; cc < 2; ++cc) {
        const int c = wave * 2 + cc;
        gload_lds16(gB + (size_t)(cc * 16) * DIM_, Bs[0] + c * 512);
    }
    #pragma unroll
    for (int kt = 0; kt < 16; ++kt) {
        const int cur = kt & 1;
        __syncthreads();      // vmcnt(0) drain: buf[cur] staged & visible;
                              // all waves done reading buf[cur^1]
        if (kt < 15) {        // prefetch kt+1 into the buffer just released
            gload_lds16(gA + (kt + 1) * 32, As[cur ^ 1] + wave * 512);
            #pragma unroll
            for (int cc = 0; cc < 2; ++cc) {
                const int c = wave * 2 + cc;
                gload_lds16(gB + (size_t)(cc * 16) * DIM_ + (kt + 1) * 32, Bs[cur ^ 1] + c * 512);
            }
        }
        bf16x8 af[4], bf[4];
        #pragma unroll
        for (int fi = 0; fi < 4; ++fi)
            af[fi] = *reinterpret_cast<const bf16x8*>(As[cur] + (wy * 64 + fi * 16 + m16) * 32 + rcol);
        #pragma unroll
        for (int fj = 0; fj < 4; ++fj)
            bf[fj] = *reinterpret_cast<const bf16x8*>(Bs[cur] + (wx * 64 + fj * 16 + m16) * 32 + rcol);
        #pragma unroll
        for (int fi = 0; fi < 4; ++fi)
            #pragma unroll
            for (int fj = 0; fj < 4; ++fj)
                acc[fi][fj] = __builtin_amdgcn_mfma_f32_16x16x32_bf16(af[fi], bf[fj], acc[fi][fj], 0, 0, 0);
    }

    // ---- epilogue ----
    const int mbase = m0 + wy * 64;              // 64-aligned -> part,h wave-uniform
    float bb[4][4];
    #pragma unroll
    for (int fi = 0; fi < 4; ++fi)
        #pragma unroll
        for (int r = 0; r < 4; ++r) bb[fi][r] = bias[mbase + fi * 16 + quad * 4 + r];

    if (QKV) {
        const int part = mbase >> 9;             // 0=q 1=k 2=v
        const int h = (mbase & 511) >> 6;
        #pragma unroll
        for (int fj = 0; fj < 4; ++fj) {
            const int j = j0 + wx * 64 + fj * 16 + m16;
            const u32 b = (u32)j / 224u;
            const int n = j - (int)b * 224;
            if (part < 2) {                      // q,k -> [b][h][n][64], 8B packed
                u16* base = (part == 0 ? o_q : o_k) + (((size_t)b * HEADS_ + h) * NP_ + n) * HD_;
                #pragma unroll
                for (int fi = 0; fi < 4; ++fi) {
                    const int d0 = fi * 16 + quad * 4;
                    uint2 pk;
                    pk.x = (u32)f2bf(acc[fi][fj][0] + bb[fi][0]) | ((u32)f2bf(acc[fi][fj][1] + bb[fi][1]) << 16);
                    pk.y = (u32)f2bf(acc[fi][fj][2] + bb[fi][2]) | ((u32)f2bf(acc[fi][fj][3] + bb[fi][3]) << 16);
                    *reinterpret_cast<uint2*>(base + d0) = pk;
                }
            } else {                             // v -> [b][h][d][224], 2B stores
                u16* vb = o_v + (((size_t)b * HEADS_ + h) * HD_) * NP_ + n;
                #pragma unroll
                for (int fi = 0; fi < 4; ++fi) {
                    const int d0 = fi * 16 + quad * 4;
                    #pragma unroll
                    for (int r = 0; r < 4; ++r)
                        vb[(size_t)(d0 + r) * NP_] = f2bf(acc[fi][fj][r] + bb[fi][r]);
                }
            }
        }
    } else {                                     // proj: fp32 out[b][512][196]
        #pragma unroll
        for (int fj = 0; fj < 4; ++fj) {
            const int j = j0 + wx * 64 + fj * 16 + m16;
            const u32 b = (u32)j / 224u;
            const int n = j - (int)b * 224;
            if (n < N_) {
                float* ob = o_f + (size_t)b * BSTRIDE + n;
                #pragma unroll
                for (int fi = 0; fi < 4; ++fi) {
                    const int r0 = mbase + fi * 16 + quad * 4;
                    #pragma unroll
                    for (int r = 0; r < 4; ++r)
                        ob[(size_t)(r0 + r) * N_] = acc[fi][fj][r] + bb[fi][r];
                }
            }
        }
    }
}

// ---------------------------------------------------------------------------
// MFMA attention per (b,h), 8 waves (512 thr). K and V staged in LDS once
// per block.
//   Ks[224][64] u16, chunk-XOR swizzled: 16B chunk ch of row r stored at
//     ch^(r&7) -> stride-128B ds_read_b128 frag reads hit the 8-pass minimum.
//   Vs[64][232] u16, +8 u16 row pad -> b128 reads minimal.
//   P[8][16*232] per-wave.
// LDS total 117.8 KB -> 1 block/CU, 8 waves = 2/SIMD; 1024 blocks = 4 rounds.
// mx over all 14 mtiles incl. pads, EB=0 masks pad m; OT stores guarded n<196.
// ---------------------------------------------------------------------------
__global__ __launch_bounds__(512) void attn_mfma(
    const u16* __restrict__ qT, const u16* __restrict__ kT,
    const u16* __restrict__ vS, const float* __restrict__ EB,
    u16* __restrict__ OT)
{
    __shared__ u16 Ks[224 * 64];        // 28.7 KB, chunk-XOR swizzled
    __shared__ u16 Vs[64 * 232];        // 29.7 KB, row-padded
    __shared__ u16 P[8][16 * 232];      // 59.4 KB
    const int t = threadIdx.x;
    const int wave = t >> 6, lane = t & 63;
    const int m16 = lane & 15, quad = lane >> 4;
    const int b = blockIdx.x, h = blockIdx.y;
    const u16* qTb = qT + ((size_t)b * HEADS_ + h) * (NP_ * HD_);
    const u16* kTb = kT + ((size_t)b * HEADS_ + h) * (NP_ * HD_);
    const u16* vb  = vS + ((size_t)b * HEADS_ + h) * (HD_ * NP_);
    const float* ebh = EB + (size_t)h * NROW_ * NP_;
    u16* Pw = P[wave];
    u16* otb = OT + (size_t)b * NP_ * DIM_ + h * HD_;
    const f32x4 z4 = {0.f, 0.f, 0.f, 0.f};

    // ---- stage K: 224 rows x 8 chunks(16B) = 1792 chunks over 512 thr ----
    #pragma unroll
    for (int i = 0; i < 4; ++i) {
        const int c = t + i * 512;
        if (c < 1792) {
            const int row = c >> 3, ch = c & 7;
            const bf16x8 d = *reinterpret_cast<const bf16x8*>(kTb + row * HD_ + ch * 8);
            *reinterpret_cast<bf16x8*>(Ks + row * 64 + ((ch ^ (row & 7)) * 8)) = d;
        }
    }
    // ---- stage V: 64 rows x 28 chunks(16B) = 1792 chunks, repack to 232 ----
    #pragma unroll
    for (int i = 0; i < 4; ++i) {
        const int c = t + i * 512;
        if (c < 1792) {
            const u32 row = (u32)c / 28u;
            const int ch = c - (int)row * 28;
            const bf16x8 d = *reinterpret_cast<const bf16x8*>(vb + (size_t)row * NP_ + ch * 8);
            *reinterpret_cast<bf16x8*>(Vs + row * 232 + ch * 8) = d;
        }
    }
    __syncthreads();

    for (int nt = wave; nt < 13; nt += 8) {
        f32x4 s[14];
        #pragma unroll
        for (int mt = 0; mt < 14; ++mt) s[mt] = z4;
        #pragma unroll
        for (int ks = 0; ks < 2; ++ks) {
            const bf16x8 a = *reinterpret_cast<const bf16x8*>(
                qTb + (size_t)(nt * 16 + m16) * HD_ + ks * 32 + quad * 8);
            const int ch = ((ks * 4 + quad) ^ (m16 & 7)) * 8;   // K swizzle inverse
            #pragma unroll
            for (int mtile = 0; mtile < 14; ++mtile) {
                const bf16x8 bf = *reinterpret_cast<const bf16x8*>(
                    Ks + (mtile * 16 + m16) * 64 + ch);
                s[mtile] = __builtin_amdgcn_mfma_f32_16x16x32_bf16(a, bf, s[mtile], 0, 0, 0);
            }
        }
        float mx[4] = {-INFINITY, -INFINITY, -INFINITY, -INFINITY};
        #pragma unroll
        for (int mt = 0; mt < 14; ++mt)
            #pragma unroll
            for (int r = 0; r < 4; ++r) mx[r] = fmaxf(mx[r], s[mt][r]);
        #pragma unroll
        for (int off = 1; off < 16; off <<= 1)
            #pragma unroll
            for (int r = 0; r < 4; ++r) mx[r] = fmaxf(mx[r], __shfl_xor(mx[r], off, 64));
        #pragma unroll
        for (int r = 0; r < 4; ++r) mx[r] *= SCALE_;

        const float* ebn = ebh + (size_t)(nt * 16 + quad * 4) * NP_ + m16;
        float sum[4] = {0.f, 0.f, 0.f, 0.f};
        #pragma unroll
        for (int mt = 0; mt < 14; ++mt) {
            #pragma unroll
            for (int r = 0; r < 4; ++r) {
                const float e = __expf(fmaf(s[mt][r], SCALE_, -mx[r])) * ebn[(size_t)r * NP_ + mt * 16];
                s[mt][r] = e;
                sum[r] += e;
            }
        }
        #pragma unroll
        for (int off = 1; off < 16; off <<= 1)
            #pragma unroll
            for (int r = 0; r < 4; ++r) sum[r] += __shfl_xor(sum[r], off, 64);
        float inv[4];
        #pragma unroll
        for (int r = 0; r < 4; ++r) inv[r] = 1.f / sum[r];

        #pragma unroll
        for (int mt = 0; mt < 14; ++mt)
            #pragma unroll
            for (int r = 0; r < 4; ++r)
                Pw[(quad * 4 + r) * 232 + mt * 16 + m16] = f2bf(s[mt][r] * inv[r]);

        f32x4 o[4];
        #pragma unroll
        for (int dt = 0; dt < 4; ++dt) o[dt] = z4;
        #pragma unroll
        for (int ks = 0; ks < 7; ++ks) {
            const bf16x8 a = *reinterpret_cast<const bf16x8*>(Pw + m16 * 232 + ks * 32 + quad * 8);
            #pragma unroll
            for (int dt = 0; dt < 4; ++dt) {
                const bf16x8 bf = *reinterpret_cast<const bf16x8*>(
                    Vs + (dt * 16 + m16) * 232 + ks * 32 + quad * 8);
                o[dt] = __builtin_amdgcn_mfma_f32_16x16x32_bf16(a, bf, o[dt], 0, 0, 0);
            }
        }
        #pragma unroll
        for (int r = 0; r < 4; ++r) {
            const int n = nt * 16 + quad * 4 + r;
            if (n < N_) {
                #pragma unroll
                for (int dt = 0; dt < 4; ++dt)
                    otb[(size_t)n * DIM_ + dt * 16 + m16] = f2bf(o[dt][r]);
            }
        }
    }
}

extern "C" void kernel_launch(void* const* d_in, const int* in_sizes, int n_in,
                              void* d_out, int out_size, void* d_ws, size_t ws_size,
                              hipStream_t stream) {
    const float* x      = (const float*)d_in[0];
    const float* qkv_w  = (const float*)d_in[1];
    const float* qkv_b  = (const float*)d_in[2];
    const float* proj_w = (const float*)d_in[3];
    const float* proj_b = (const float*)d_in[4];
    const float* biases = (const float*)d_in[5];
    const int*   bidx   = (const int*)d_in[6];
    float* out = (float*)d_out;

    // ws layout (~92 MB; 103 MB proven safe):
    char* w = (char*)d_ws;
    u16* XT  = (u16*)w; w += (size_t)B_ * NP_ * DIM_ * 2;            // 29.4 MB (reused as OT)
    u16* qTw = (u16*)w; w += (size_t)B_ * HEADS_ * NP_ * HD_ * 2;    // 29.4 MB
    u16* vSw = (u16*)w; w += (size_t)B_ * HEADS_ * HD_ * NP_ * 2;    // 29.4 MB
    float* EB = (float*)w; w += (size_t)HEADS_ * NROW_ * NP_ * 4;    // 1.5 MB
    u16* wq  = (u16*)w; w += (size_t)3 * DIM_ * DIM_ * 2;            // 1.6 MB
    u16* wpj = (u16*)w;                                              // 0.5 MB
    u16* kTw = (u16*)d_out;                                          // kT parked in d_out

    cvt_bf2<<<dim3(768, 2), 256, 0, stream>>>(qkv_w, wq, 3 * DIM_ * DIM_ / 4,
                                              proj_w, wpj, DIM_ * DIM_ / 4);
    cvt_xT<<<dim3(8, 4, B_), 256, 0, stream>>>(x, XT);
    mk_eb<<<dim3(NROW_, HEADS_), 256, 0, stream>>>(biases, bidx, EB);
    gemm128<true><<<dim3((J_ / 256) * 12), 512, 0, stream>>>(XT, wq, qkv_b, qTw, kTw, vSw, nullptr);
    attn_mfma<<<dim3(B_, HEADS_), 512, 0, stream>>>(qTw, kTw, vSw, EB, XT);
    gemm128<false><<<dim3((J_ / 256) * 4), 512, 0, stream>>>(XT, wpj, proj_b, nullptr, nullptr, nullptr, out);
}

// Round 6
// 292.241 us; speedup vs baseline: 1.0401x; 1.0401x over previous
//
#include <hip/hip_runtime.h>
#include <hip/hip_bf16.h>
#include <math.h>

#define B_     128
#define DIM_   512
#define HEADS_ 8
#define HD_    64
#define N_     196
#define NP_    224            // padded n (14 tiles of 16)
#define NROW_  208            // padded n rows (13 tiles of 16) for EB
#define SCALE_ 0.125f
#define BSTRIDE (DIM_ * N_)
#define J_     (B_ * NP_)     // 28672 GEMM columns (b*224+n)

typedef unsigned short u16;
typedef unsigned int   u32;
typedef __attribute__((ext_vector_type(8))) short bf16x8;   // 8 bf16 = 4 VGPRs
typedef __attribute__((ext_vector_type(4))) float f32x4;

__device__ __forceinline__ u16 f2bf(float f) {              // RNE fp32->bf16
    u32 u = __float_as_uint(f);
    return (u16)((u + 0x7fffu + ((u >> 16) & 1u)) >> 16);
}

// ---------------------------------------------------------------------------
// Frag-major layout (new in r11): FM[row/16][k/32][quad][m16][8 bf16].
// u16 addr(row,k) = (row>>4)*8192 + (k>>5)*512 + ((k>>3)&3)*128 + (row&15)*8
//                 + (k&7)        [K=512 fixed -> 16 kb slots]
// One MFMA fragment (16 rows x 8 k for 64 lanes) = 1 KB CONTIGUOUS ->
// global_load_dwordx4 per frag, fully coalesced, no LDS, no barriers.
// ---------------------------------------------------------------------------

// fp32 weights -> frag-major bf16. dst chunk index == thread index (layout
// decode t = mb*1024 + kb*64 + q*16 + m16 equals addr/8). y=0: qkv, y=1: proj.
__global__ __launch_bounds__(256) void cvt_w2(
    const float* __restrict__ qw, u16* __restrict__ qd,
    const float* __restrict__ pw, u16* __restrict__ pd)
{
    const float* src = blockIdx.y ? pw : qw;
    u16* dst = blockIdx.y ? pd : qd;
    const int nch = blockIdx.y ? (DIM_ * DIM_ / 8) : (3 * DIM_ * DIM_ / 8);
    const int t = blockIdx.x * 256 + threadIdx.x;
    if (t < nch) {
        const int m16 = t & 15, q = (t >> 4) & 3, kb = (t >> 6) & 15, mb = t >> 10;
        const float* s = src + (size_t)(mb * 16 + m16) * DIM_ + kb * 32 + q * 8;
        const float4 v0 = reinterpret_cast<const float4*>(s)[0];
        const float4 v1 = reinterpret_cast<const float4*>(s)[1];
        uint4 o;
        o.x = (u32)f2bf(v0.x) | ((u32)f2bf(v0.y) << 16);
        o.y = (u32)f2bf(v0.z) | ((u32)f2bf(v0.w) << 16);
        o.z = (u32)f2bf(v1.x) | ((u32)f2bf(v1.y) << 16);
        o.w = (u32)f2bf(v1.z) | ((u32)f2bf(v1.w) << 16);
        reinterpret_cast<uint4*>(dst)[t] = o;
    }
}

// ---------------------------------------------------------------------------
// x fp32 [b][512][196] -> XT2 frag-major bf16 over rows j=b*224+n (pad rows
// unwritten garbage, masked downstream: EB=0 for m>=196, OT/out guarded).
// Load phase (LDS transpose) unchanged from the verified cvt_xT; write phase
// emits 16B frag-major chunks (16 consecutive threads -> 256 B contiguous).
// ---------------------------------------------------------------------------
__global__ __launch_bounds__(256) void cvt_xT(
    const float* __restrict__ x, u16* __restrict__ XT)
{
    __shared__ float tile[64][65];
    const int t = threadIdx.x;
    const int jj = t & 63, ii = t >> 6;
    const int ct = blockIdx.x, ntb = blockIdx.y, b = blockIdx.z;
    const float* xb = x + ((size_t)b * DIM_ + ct * 64) * N_;
    const int n0 = ntb * 64;
    #pragma unroll
    for (int s = 0; s < 16; ++s) {
        const int i = ii + s * 4;
        const int n = n0 + jj;
        tile[i][jj] = (n < N_) ? xb[(size_t)i * N_ + n] : 0.f;
    }
    __syncthreads();
    const int lo = t & 15, hi = t >> 4;
    const int c8 = hi & 7, ng = hi >> 3;
    #pragma unroll
    for (int s = 0; s < 2; ++s) {
        const int n_loc = (s * 2 + ng) * 16 + lo;
        const int nn = n0 + n_loc;
        if (nn < N_) {
            const int j = b * NP_ + nn;                 // NP_,n0 mult of 16 -> j&15==lo
            const int c0 = ct * 64 + c8 * 8;
            u16 vv[8];
            #pragma unroll
            for (int e = 0; e < 8; ++e) vv[e] = f2bf(tile[c8 * 8 + e][n_loc]);
            uint4 o;
            o.x = (u32)vv[0] | ((u32)vv[1] << 16);
            o.y = (u32)vv[2] | ((u32)vv[3] << 16);
            o.z = (u32)vv[4] | ((u32)vv[5] << 16);
            o.w = (u32)vv[6] | ((u32)vv[7] << 16);
            *reinterpret_cast<uint4*>(XT + (size_t)(j >> 4) * 8192
                + (c0 >> 5) * 512 + ((c0 >> 3) & 3) * 128 + (j & 15) * 8) = o;
        }
    }
}

// ---------------------------------------------------------------------------
// EB[h][208][224] = exp(bias[h][bidx[n][m]]) for n,m<196 else 0.
// ---------------------------------------------------------------------------
__global__ __launch_bounds__(256) void mk_eb(
    const float* __restrict__ biases, const int* __restrict__ bidx,
    float* __restrict__ EB)
{
    const int n = blockIdx.x, h = blockIdx.y;
    const int m = threadIdx.x;
    if (m < NP_) {
        float v = 0.f;
        if (n < N_ && m < N_) v = __expf(biases[h * N_ + bidx[n * N_ + m]]);
        EB[((size_t)h * NROW_ + n) * NP_ + m] = v;
    }
}

// ---------------------------------------------------------------------------
// r11: register-direct 128x128 MFMA GEMM, NO LDS / NO BARRIERS.
// Why: r8's 2-phase loop spent ~72% in stage+vmcnt(0)+barrier (true MFMA
// floor 21.7us of 78; r9 deeper pipeline and r10 more waves both regressed
// -- the lockstep structure itself was the cost). With frag-major operands,
// each fragment is one coalesced global_load_dwordx4 (1 KB/instr); the
// kt-loop is 8 loads + 16 MFMA with waves free-running. Load latency hides
// under the ~310cy MFMA issue block of the previous iteration (in-order
// issue); intra-block duplicate frags (2x) hit L1 (16 KB/kt < 32 KB L1);
// cross-mt B-panel reuse stays in L2 via the verified XCD swizzle
// (mt-fastest, bijective, NWG%8==0; FETCH 87->34 MB in r8).
// Frag element mapping == old staged path (slot-XOR o read-XOR = identity:
// k-cols kt*32+quad*8+e) -> MFMA + verified epilogues untouched.
// Epilogue QKV: qT/kT[b][h][n<=224][64] (8B stores), vS[b][h][d][224];
// pads stored unguarded -- EB=0 masks every pad contribution downstream.
// Epilogue proj: fp32 out[b][512][196], n guarded.
// ---------------------------------------------------------------------------
template<bool QKV>
__global__ __launch_bounds__(256) void gemm128(
    const u16* __restrict__ Bt, const u16* __restrict__ W,
    const float* __restrict__ bias,
    u16* __restrict__ o_q, u16* __restrict__ o_k, u16* __restrict__ o_v,
    float* __restrict__ o_f)
{
    const int t = threadIdx.x;
    const int wave = t >> 6, lane = t & 63;
    const int m16 = lane & 15, quad = lane >> 4;

    constexpr int MT  = QKV ? 12 : 4;
    constexpr int NWG = (J_ / 128) * MT;
    const int bid = blockIdx.x;
    const int swz = (bid & 7) * (NWG / 8) + (bid >> 3);   // bijective XCD swizzle
    const int mt = swz % MT;                               // mt fastest
    const int jt = swz / MT;
    const int m0 = mt * 128, j0 = jt * 128;
    const int wy = wave >> 1, wx = wave & 1;     // wave tile: rows wy*64, cols wx*64

    // frag-major bases: frag(fi,kt) at base + fi*8192 + kt*512 (u16 units)
    const u16* A2 = W  + (size_t)(mt * 8 + wy * 4) * 8192 + quad * 128 + m16 * 8;
    const u16* B2 = Bt + (size_t)(jt * 8 + wx * 4) * 8192 + quad * 128 + m16 * 8;

    f32x4 acc[4][4];
    const f32x4 z4 = {0.f, 0.f, 0.f, 0.f};
    #pragma unroll
    for (int fi = 0; fi < 4; ++fi)
        #pragma unroll
        for (int fj = 0; fj < 4; ++fj) acc[fi][fj] = z4;

    #pragma unroll
    for (int kt = 0; kt < 16; ++kt) {
        bf16x8 af[4], bf[4];
        #pragma unroll
        for (int fi = 0; fi < 4; ++fi)
            af[fi] = *reinterpret_cast<const bf16x8*>(A2 + fi * 8192 + kt * 512);
        #pragma unroll
        for (int fj = 0; fj < 4; ++fj)
            bf[fj] = *reinterpret_cast<const bf16x8*>(B2 + fj * 8192 + kt * 512);
        #pragma unroll
        for (int fi = 0; fi < 4; ++fi)
            #pragma unroll
            for (int fj = 0; fj < 4; ++fj)
                acc[fi][fj] = __builtin_amdgcn_mfma_f32_16x16x32_bf16(af[fi], bf[fj], acc[fi][fj], 0, 0, 0);
    }

    // ---- epilogue ----
    const int mbase = m0 + wy * 64;              // 64-aligned -> part,h wave-uniform
    float bb[4][4];
    #pragma unroll
    for (int fi = 0; fi < 4; ++fi)
        #pragma unroll
        for (int r = 0; r < 4; ++r) bb[fi][r] = bias[mbase + fi * 16 + quad * 4 + r];

    if (QKV) {
        const int part = mbase >> 9;             // 0=q 1=k 2=v
        const int h = (mbase & 511) >> 6;
        #pragma unroll
        for (int fj = 0; fj < 4; ++fj) {
            const int j = j0 + wx * 64 + fj * 16 + m16;
            const u32 b = (u32)j / 224u;
            const int n = j - (int)b * 224;
            if (part < 2) {                      // q,k -> [b][h][n][64], 8B packed
                u16* base = (part == 0 ? o_q : o_k) + (((size_t)b * HEADS_ + h) * NP_ + n) * HD_;
                #pragma unroll
                for (int fi = 0; fi < 4; ++fi) {
                    const int d0 = fi * 16 + quad * 4;
                    uint2 pk;
                    pk.x = (u32)f2bf(acc[fi][fj][0] + bb[fi][0]) | ((u32)f2bf(acc[fi][fj][1] + bb[fi][1]) << 16);
                    pk.y = (u32)f2bf(acc[fi][fj][2] + bb[fi][2]) | ((u32)f2bf(acc[fi][fj][3] + bb[fi][3]) << 16);
                    *reinterpret_cast<uint2*>(base + d0) = pk;
                }
            } else {                             // v -> [b][h][d][224], 2B stores
                u16* vb = o_v + (((size_t)b * HEADS_ + h) * HD_) * NP_ + n;
                #pragma unroll
                for (int fi = 0; fi < 4; ++fi) {
                    const int d0 = fi * 16 + quad * 4;
                    #pragma unroll
                    for (int r = 0; r < 4; ++r)
                        vb[(size_t)(d0 + r) * NP_] = f2bf(acc[fi][fj][r] + bb[fi][r]);
                }
            }
        }
    } else {                                     // proj: fp32 out[b][512][196]
        #pragma unroll
        for (int fj = 0; fj < 4; ++fj) {
            const int j = j0 + wx * 64 + fj * 16 + m16;
            const u32 b = (u32)j / 224u;
            const int n = j - (int)b * 224;
            if (n < N_) {
                float* ob = o_f + (size_t)b * BSTRIDE + n;
                #pragma unroll
                for (int fi = 0; fi < 4; ++fi) {
                    const int r0 = mbase + fi * 16 + quad * 4;
                    #pragma unroll
                    for (int r = 0; r < 4; ++r)
                        ob[(size_t)(r0 + r) * N_] = acc[fi][fj][r] + bb[fi][r];
                }
            }
        }
    }
}

// ---------------------------------------------------------------------------
// MFMA attention per (b,h), 8 waves (512 thr). K and V staged in LDS once
// per block (verified r6 structure). Only change in r11: OT output store is
// frag-major (feeds proj's register-direct B reads); scalar 2B stores either
// way, same count.
//   Ks[224][64] u16, chunk-XOR swizzled; Vs[64][232] row-padded;
//   P[8][16*232] per-wave. LDS 117.8 KB -> 1 block/CU.
// mx over all 14 mtiles incl. pads, EB=0 masks pad m; OT stores guarded n<196.
// ---------------------------------------------------------------------------
__global__ __launch_bounds__(512) void attn_mfma(
    const u16* __restrict__ qT, const u16* __restrict__ kT,
    const u16* __restrict__ vS, const float* __restrict__ EB,
    u16* __restrict__ OT)
{
    __shared__ u16 Ks[224 * 64];        // 28.7 KB, chunk-XOR swizzled
    __shared__ u16 Vs[64 * 232];        // 29.7 KB, row-padded
    __shared__ u16 P[8][16 * 232];      // 59.4 KB
    const int t = threadIdx.x;
    const int wave = t >> 6, lane = t & 63;
    const int m16 = lane & 15, quad = lane >> 4;
    const int b = blockIdx.x, h = blockIdx.y;
    const u16* qTb = qT + ((size_t)b * HEADS_ + h) * (NP_ * HD_);
    const u16* kTb = kT + ((size_t)b * HEADS_ + h) * (NP_ * HD_);
    const u16* vb  = vS + ((size_t)b * HEADS_ + h) * (HD_ * NP_);
    const float* ebh = EB + (size_t)h * NROW_ * NP_;
    u16* Pw = P[wave];
    const f32x4 z4 = {0.f, 0.f, 0.f, 0.f};

    // ---- stage K: 224 rows x 8 chunks(16B) = 1792 chunks over 512 thr ----
    #pragma unroll
    for (int i = 0; i < 4; ++i) {
        const int c = t + i * 512;
        if (c < 1792) {
            const int row = c >> 3, ch = c & 7;
            const bf16x8 d = *reinterpret_cast<const bf16x8*>(kTb + row * HD_ + ch * 8);
            *reinterpret_cast<bf16x8*>(Ks + row * 64 + ((ch ^ (row & 7)) * 8)) = d;
        }
    }
    // ---- stage V: 64 rows x 28 chunks(16B) = 1792 chunks, repack to 232 ----
    #pragma unroll
    for (int i = 0; i < 4; ++i) {
        const int c = t + i * 512;
        if (c < 1792) {
            const u32 row = (u32)c / 28u;
            const int ch = c - (int)row * 28;
            const bf16x8 d = *reinterpret_cast<const bf16x8*>(vb + (size_t)row * NP_ + ch * 8);
            *reinterpret_cast<bf16x8*>(Vs + row * 232 + ch * 8) = d;
        }
    }
    __syncthreads();

    for (int nt = wave; nt < 13; nt += 8) {
        f32x4 s[14];
        #pragma unroll
        for (int mt = 0; mt < 14; ++mt) s[mt] = z4;
        #pragma unroll
        for (int ks = 0; ks < 2; ++ks) {
            const bf16x8 a = *reinterpret_cast<const bf16x8*>(
                qTb + (size_t)(nt * 16 + m16) * HD_ + ks * 32 + quad * 8);
            const int ch = ((ks * 4 + quad) ^ (m16 & 7)) * 8;   // K swizzle inverse
            #pragma unroll
            for (int mtile = 0; mtile < 14; ++mtile) {
                const bf16x8 bf = *reinterpret_cast<const bf16x8*>(
                    Ks + (mtile * 16 + m16) * 64 + ch);
                s[mtile] = __builtin_amdgcn_mfma_f32_16x16x32_bf16(a, bf, s[mtile], 0, 0, 0);
            }
        }
        float mx[4] = {-INFINITY, -INFINITY, -INFINITY, -INFINITY};
        #pragma unroll
        for (int mt = 0; mt < 14; ++mt)
            #pragma unroll
            for (int r = 0; r < 4; ++r) mx[r] = fmaxf(mx[r], s[mt][r]);
        #pragma unroll
        for (int off = 1; off < 16; off <<= 1)
            #pragma unroll
            for (int r = 0; r < 4; ++r) mx[r] = fmaxf(mx[r], __shfl_xor(mx[r], off, 64));
        #pragma unroll
        for (int r = 0; r < 4; ++r) mx[r] *= SCALE_;

        const float* ebn = ebh + (size_t)(nt * 16 + quad * 4) * NP_ + m16;
        float sum[4] = {0.f, 0.f, 0.f, 0.f};
        #pragma unroll
        for (int mt = 0; mt < 14; ++mt) {
            #pragma unroll
            for (int r = 0; r < 4; ++r) {
                const float e = __expf(fmaf(s[mt][r], SCALE_, -mx[r])) * ebn[(size_t)r * NP_ + mt * 16];
                s[mt][r] = e;
                sum[r] += e;
            }
        }
        #pragma unroll
        for (int off = 1; off < 16; off <<= 1)
            #pragma unroll
            for (int r = 0; r < 4; ++r) sum[r] += __shfl_xor(sum[r], off, 64);
        float inv[4];
        #pragma unroll
        for (int r = 0; r < 4; ++r) inv[r] = 1.f / sum[r];

        #pragma unroll
        for (int mt = 0; mt < 14; ++mt)
            #pragma unroll
            for (int r = 0; r < 4; ++r)
                Pw[(quad * 4 + r) * 232 + mt * 16 + m16] = f2bf(s[mt][r] * inv[r]);

        f32x4 o[4];
        #pragma unroll
        for (int dt = 0; dt < 4; ++dt) o[dt] = z4;
        #pragma unroll
        for (int ks = 0; ks < 7; ++ks) {
            const bf16x8 a = *reinterpret_cast<const bf16x8*>(Pw + m16 * 232 + ks * 32 + quad * 8);
            #pragma unroll
            for (int dt = 0; dt < 4; ++dt) {
                const bf16x8 bf = *reinterpret_cast<const bf16x8*>(
                    Vs + (dt * 16 + m16) * 232 + ks * 32 + quad * 8);
                o[dt] = __builtin_amdgcn_mfma_f32_16x16x32_bf16(a, bf, o[dt], 0, 0, 0);
            }
        }
        #pragma unroll
        for (int r = 0; r < 4; ++r) {
            const int n = nt * 16 + quad * 4 + r;
            if (n < N_) {
                const int j = b * NP_ + n;
                #pragma unroll
                for (int dt = 0; dt < 4; ++dt) {
                    const int c = h * HD_ + dt * 16 + m16;
                    OT[(size_t)(j >> 4) * 8192 + (c >> 5) * 512
                       + ((c >> 3) & 3) * 128 + (j & 15) * 8 + (c & 7)] = f2bf(o[dt][r]);
                }
            }
        }
    }
}

extern "C" void kernel_launch(void* const* d_in, const int* in_sizes, int n_in,
                              void* d_out, int out_size, void* d_ws, size_t ws_size,
                              hipStream_t stream) {
    const float* x      = (const float*)d_in[0];
    const float* qkv_w  = (const float*)d_in[1];
    const float* qkv_b  = (const float*)d_in[2];
    const float* proj_w = (const float*)d_in[3];
    const float* proj_b = (const float*)d_in[4];
    const float* biases = (const float*)d_in[5];
    const int*   bidx   = (const int*)d_in[6];
    float* out = (float*)d_out;

    // ws layout (~92 MB; 103 MB proven safe):
    char* w = (char*)d_ws;
    u16* XT  = (u16*)w; w += (size_t)B_ * NP_ * DIM_ * 2;            // 29.4 MB frag-major (reused as OT)
    u16* qTw = (u16*)w; w += (size_t)B_ * HEADS_ * NP_ * HD_ * 2;    // 29.4 MB
    u16* vSw = (u16*)w; w += (size_t)B_ * HEADS_ * HD_ * NP_ * 2;    // 29.4 MB
    float* EB = (float*)w; w += (size_t)HEADS_ * NROW_ * NP_ * 4;    // 1.5 MB
    u16* wq  = (u16*)w; w += (size_t)3 * DIM_ * DIM_ * 2;            // 1.6 MB frag-major
    u16* wpj = (u16*)w;                                              // 0.5 MB frag-major
    u16* kTw = (u16*)d_out;                                          // kT parked in d_out

    cvt_w2<<<dim3(384, 2), 256, 0, stream>>>(qkv_w, wq, proj_w, wpj);
    cvt_xT<<<dim3(8, 4, B_), 256, 0, stream>>>(x, XT);
    mk_eb<<<dim3(NROW_, HEADS_), 256, 0, stream>>>(biases, bidx, EB);
    gemm128<true><<<dim3((J_ / 128) * 12), 256, 0, stream>>>(XT, wq, qkv_b, qTw, kTw, vSw, nullptr);
    attn_mfma<<<dim3(B_, HEADS_), 512, 0, stream>>>(qTw, kTw, vSw, EB, XT);
    gemm128<false><<<dim3((J_ / 128) * 4), 256, 0, stream>>>(XT, wpj, proj_b, nullptr, nullptr, nullptr, out);
}